// Round 12
// baseline (759.408 us; speedup 1.0000x reference)
//
#include <hip/hip_runtime.h>
#include <hip/hip_bf16.h>

#define NE 8
#define FF 4096
#define HH 2048
#define TT 2048
#define KTOP 4

typedef unsigned short u16;
typedef unsigned int u32;
typedef __attribute__((ext_vector_type(8))) short bf16x8;
typedef __attribute__((ext_vector_type(4))) float f32x4;

#define CFENCE asm volatile("" ::: "memory")

__device__ __forceinline__ u16 f2u(float f) {
  __hip_bfloat16 b = __float2bfloat16(f);
  return *reinterpret_cast<u16*>(&b);
}
__device__ __forceinline__ float u2f(u16 u) {
  union { u32 i; float f; } c; c.i = ((u32)u) << 16; return c.f;
}

__device__ __forceinline__ void gld16(void* lds, const void* g) {
  __builtin_amdgcn_global_load_lds(
      (const __attribute__((address_space(1))) void*)g,
      (__attribute__((address_space(3))) void*)lds, 16, 0, 0);
}

__device__ __forceinline__ void vmwait(int n) {
  switch (n) {
    case 0:  asm volatile("s_waitcnt vmcnt(0)"  ::: "memory"); break;
    case 6:  asm volatile("s_waitcnt vmcnt(6)"  ::: "memory"); break;
    default: asm volatile("s_waitcnt vmcnt(8)"  ::: "memory"); break;
  }
}

// Per-expert token lists, deterministic (token ascending).
__global__ void k_build(const int* __restrict__ te, int* __restrict__ cnt,
                        int* __restrict__ tok, int* __restrict__ posmap) {
  const int e = blockIdx.x;
  const int tl = threadIdx.x;
  const int base = tl * 8;
  int mem[8];
  int my = 0;
  #pragma unroll
  for (int i = 0; i < 8; ++i) {
    const int t = base + i;
    bool m = false;
    #pragma unroll
    for (int k = 0; k < KTOP; ++k) m |= (te[t * KTOP + k] == e);
    mem[i] = m ? 1 : 0;
    my += mem[i];
  }
  __shared__ int s[256];
  s[tl] = my;
  __syncthreads();
  for (int off = 1; off < 256; off <<= 1) {
    int v = (tl >= off) ? s[tl - off] : 0;
    __syncthreads();
    s[tl] += v;
    __syncthreads();
  }
  int r = s[tl] - my;
  if (tl == 255) cnt[e] = s[255];
  #pragma unroll
  for (int i = 0; i < 8; ++i) {
    if (mem[i]) {
      const int t = base + i;
      tok[e * TT + r] = t;
      posmap[t * NE + e] = r;
      ++r;
    }
  }
}

__global__ void k_cast4(const float4* __restrict__ src, ushort4* __restrict__ dst, int n4) {
  int stride = gridDim.x * blockDim.x;
  for (int i = blockIdx.x * blockDim.x + threadIdx.x; i < n4; i += stride) {
    float4 f = src[i];
    ushort4 o;
    o.x = f2u(f.x); o.y = f2u(f.y); o.z = f2u(f.z); o.w = f2u(f.w);
    dst[i] = o;
  }
}

// ---- chain block bodies (verbatim R11 logic, re-plumbed) ----

// transpose-cast slice: w2[e][FF][HH] fp32 -> w2t[e][HH][FF] bf16.
// 256 blocks per expert, 8 64x64 tiles per block.
__device__ __forceinline__ void tcast_block(int lbid, int e0, u16* smem,
                                            const float* __restrict__ W2,
                                            u16* __restrict__ W2t) {
  float (*tile)[65] = reinterpret_cast<float(*)[65]>(smem);
  const int tid = threadIdx.x;
  const int r = tid >> 3;
  const int c0 = (tid & 7) * 8;
  for (int i = 0; i < 8; ++i) {
    const int g = e0 * 2048 + lbid * 8 + i;
    const int e = g >> 11;
    const int rem = g & 2047;
    const int f0 = (rem >> 5) << 6;
    const int h0 = (rem & 31) << 6;
    const float* src = W2 + (size_t)e * FF * HH + (size_t)(f0 + r) * HH + h0 + c0;
    float4 a = ((const float4*)src)[0];
    float4 b = ((const float4*)src)[1];
    tile[r][c0 + 0] = a.x; tile[r][c0 + 1] = a.y;
    tile[r][c0 + 2] = a.z; tile[r][c0 + 3] = a.w;
    tile[r][c0 + 4] = b.x; tile[r][c0 + 5] = b.y;
    tile[r][c0 + 6] = b.z; tile[r][c0 + 7] = b.w;
    __syncthreads();
    union { ushort u[8]; bf16x8 v; } o;
    #pragma unroll
    for (int j = 0; j < 8; ++j) o.u[j] = f2u(tile[c0 + j][r]);
    *(bf16x8*)(W2t + (size_t)e * HH * FF + (size_t)(h0 + r) * FF + f0 + c0) = o.v;
    __syncthreads();
  }
}

// GLU GEMM block (2 experts per launch, 512 blocks: 256/expert = 32 ntl x 8 mt).
// A gathered from xb via tok (zero page pads); B reg-staged from W1/V1 fp32.
// 2-barrier K-tile, counted vmcnt, granule swizzle. Out: hc bf16 silu-fused.
__device__ __forceinline__ void glu_block(int lbid, int e0, u16* smem,
    const u16* __restrict__ xb, const int* __restrict__ cnt,
    const int* __restrict__ tok, const u16* __restrict__ Zp,
    u16* __restrict__ hc, const float* __restrict__ W1,
    const float* __restrict__ V1) {
  constexpr int KD = HH, NTK = HH / 64;
  const int swz = (lbid & 7) * 64 + (lbid >> 3);
  const int e   = e0 + (swz >> 8);
  const int rem = swz & 255;
  const int ntl = rem >> 3;
  const int mt  = rem & 7;
  const int c = cnt[e];
  const int mcap = (c + 255) & ~255;
  if (mt * 256 >= mcap) return;

  const int tid  = threadIdx.x;
  const int lane = tid & 63;
  const int wave = tid >> 6;
  const int wm = wave >> 2;
  const int wn = wave & 3;

  const int tq = tid >> 2;
  const int tc = (((tid & 3) ^ ((tid >> 3) & 3)) << 3);

  const int r0 = mt * 256 + tq;
  const int r1 = r0 + 128;
  const u16* pA0 = ((r0 < c) ? xb + (size_t)tok[e * TT + r0] * HH : Zp) + tc;
  const u16* pA1 = ((r1 < c) ? xb + (size_t)tok[e * TT + r1] * HH : Zp) + tc;

  auto stageA = [&](int d, int ks, int kt) {
    u16* dst = smem + ((d * 2 + ks) << 13) + tid * 8;
    const int off = kt * 64 + ks * 32;
    gld16(dst,        pA0 + off);
    gld16(dst + 4096, pA1 + off);
  };

  const int sel = (tq >> 4) & 1;
  const int fr  = ntl * 128 + (tq >> 5) * 16 + (tq & 15);
  const float* pW = (sel ? V1 : W1) + ((size_t)(e * FF + fr)) * HH + (tid & 3) * 8;

  float4 br0[4], br1[4];
  auto issueB = [&](float4* br, int ks, int kt) {
    const float* s = pW + kt * 64 + ks * 32;
    br[0] = ((const float4*)s)[0];
    br[1] = ((const float4*)s)[1];
    const float* s2 = s + (size_t)64 * HH;
    br[2] = ((const float4*)s2)[0];
    br[3] = ((const float4*)s2)[1];
  };
  auto cvtB = [&](float4* br, int d, int ks) {
    u16* dst = smem + 32768 + ((d * 2 + ks) << 13) + tq * 32 + tc;
    union { ushort u[8]; bf16x8 v; } lo, hi;
    lo.u[0]=f2u(br[0].x); lo.u[1]=f2u(br[0].y); lo.u[2]=f2u(br[0].z); lo.u[3]=f2u(br[0].w);
    lo.u[4]=f2u(br[1].x); lo.u[5]=f2u(br[1].y); lo.u[6]=f2u(br[1].z); lo.u[7]=f2u(br[1].w);
    hi.u[0]=f2u(br[2].x); hi.u[1]=f2u(br[2].y); hi.u[2]=f2u(br[2].z); hi.u[3]=f2u(br[2].w);
    hi.u[4]=f2u(br[3].x); hi.u[5]=f2u(br[3].y); hi.u[6]=f2u(br[3].z); hi.u[7]=f2u(br[3].w);
    *(bf16x8*)(dst)        = lo.v;
    *(bf16x8*)(dst + 4096) = hi.v;
  };

  f32x4 acc[8][4];
  #pragma unroll
  for (int m = 0; m < 8; ++m)
    #pragma unroll
    for (int n = 0; n < 4; ++n)
      acc[m][n] = (f32x4){0.f, 0.f, 0.f, 0.f};

  const int lr = lane & 15;
  const int lc = ((((lane >> 4) & 3) ^ ((lane >> 1) & 3)) << 3);

  bf16x8 af[4], bf[4];
  auto rdA = [&](int d, int ks, int mq) {
    const u16* blk = smem + ((d * 2 + ks) << 13);
    #pragma unroll
    for (int m = 0; m < 4; ++m)
      af[m] = *(const bf16x8*)(blk + (wm * 128 + mq * 64 + m * 16 + lr) * 32 + lc);
  };
  auto rdB = [&](int d, int ks) {
    const u16* blk = smem + 32768 + ((d * 2 + ks) << 13);
    #pragma unroll
    for (int n = 0; n < 4; ++n)
      bf[n] = *(const bf16x8*)(blk + (wn * 64 + n * 16 + lr) * 32 + lc);
  };
  auto MF = [&](int mq) {
    __builtin_amdgcn_s_setprio(1);
    #pragma unroll
    for (int m = 0; m < 4; ++m)
      #pragma unroll
      for (int n = 0; n < 4; ++n)
        acc[mq * 4 + m][n] = __builtin_amdgcn_mfma_f32_16x16x32_bf16(
            af[m], bf[n], acc[mq * 4 + m][n], 0, 0, 0);
    __builtin_amdgcn_s_setprio(0);
  };

  // prologue
  issueB(br0, 0, 0);
  issueB(br1, 1, 0);
  stageA(0, 0, 0);
  stageA(0, 1, 0);
  cvtB(br0, 0, 0);
  cvtB(br1, 0, 1);
  issueB(br0, 0, 1);
  issueB(br1, 1, 1);
  vmwait(8);
  asm volatile("s_waitcnt lgkmcnt(0)" ::: "memory");
  __builtin_amdgcn_s_barrier();
  CFENCE;

  for (int t = 0; t < NTK; ++t) {
    const int d = t & 1, dn = d ^ 1;
    const bool hasN  = (t + 1 < NTK);
    const bool hasN2 = (t + 2 < NTK);
    rdB(d, 0); rdA(d, 0, 0);
    if (hasN) { stageA(dn, 0, t + 1); stageA(dn, 1, t + 1); }
    __builtin_amdgcn_sched_barrier(0);
    MF(0);
    rdA(d, 0, 1);
    MF(1);
    if (hasN)  cvtB(br0, dn, 0);
    if (hasN2) issueB(br0, 0, t + 2);
    rdB(d, 1); rdA(d, 1, 0);
    MF(0);
    if (hasN)  cvtB(br1, dn, 1);
    if (hasN2) issueB(br1, 1, t + 2);
    rdA(d, 1, 1);
    MF(1);
    asm volatile("s_waitcnt lgkmcnt(0)" ::: "memory");
    vmwait(hasN2 ? 8 : 0);
    __builtin_amdgcn_s_barrier();
    CFENCE;
  }

  u16* H = hc + (size_t)e * TT * FF;
  const int rb = mt * 256 + wm * 128 + ((lane >> 4) << 2);
  const int fb = ntl * 128 + wn * 32 + lr;
  #pragma unroll
  for (int m = 0; m < 8; ++m)
    #pragma unroll
    for (int np = 0; np < 2; ++np)
      #pragma unroll
      for (int j = 0; j < 4; ++j) {
        float g = acc[m][2*np][j];
        float u = acc[m][2*np + 1][j];
        float hh = (g / (1.f + __expf(-g))) * u;
        H[(size_t)(rb + m*16 + j) * FF + fb + np*16] = f2u(hh);
      }
}

// down GEMM block (2 experts per launch, 128 blocks: 64/expert = 8 ntl x 8 mt).
// A=hc, B=w2t, both gld_lds; out dcomp bf16.
__device__ __forceinline__ void down_block(int lbid, int e0, u16* smem,
    const u16* __restrict__ hc, const u16* __restrict__ w2t,
    const int* __restrict__ cnt, u16* __restrict__ dcomp) {
  constexpr int KD = FF, NTK = FF / 64;
  const int swz = (lbid & 7) * 16 + (lbid >> 3);
  const int e   = e0 + (swz >> 6);
  const int rem = swz & 63;
  const int ntl = rem >> 3;
  const int mt  = rem & 7;
  const int c = cnt[e];
  const int mcap = (c + 255) & ~255;
  if (mt * 256 >= mcap) return;

  const int tid  = threadIdx.x;
  const int lane = tid & 63;
  const int wave = tid >> 6;
  const int wm = wave >> 2;
  const int wn = wave & 3;

  const int tq = tid >> 2;
  const int tc = (((tid & 3) ^ ((tid >> 3) & 3)) << 3);

  const u16* A = hc + (size_t)e * TT * KD + (size_t)(mt * 256) * KD;
  const u16* pA0 = A + (size_t)tq * KD + tc;
  const u16* pA1 = pA0 + (size_t)128 * KD;
  const u16* pB = w2t + (size_t)e * HH * KD + (size_t)(ntl * 256) * KD
                      + (size_t)tq * KD + tc;

  auto stageA = [&](int d, int ks, int kt) {
    u16* dst = smem + ((d * 2 + ks) << 13) + tid * 8;
    const int off = kt * 64 + ks * 32;
    gld16(dst,        pA0 + off);
    gld16(dst + 4096, pA1 + off);
  };
  auto stageB = [&](int d, int ks, int kt) {
    u16* dst = smem + 32768 + ((d * 2 + ks) << 13) + tid * 8;
    const u16* src = pB + kt * 64 + ks * 32;
    gld16(dst,        src);
    gld16(dst + 4096, src + (size_t)128 * KD);
  };

  f32x4 acc[8][4];
  #pragma unroll
  for (int m = 0; m < 8; ++m)
    #pragma unroll
    for (int n = 0; n < 4; ++n)
      acc[m][n] = (f32x4){0.f, 0.f, 0.f, 0.f};

  const int lr = lane & 15;
  const int lc = ((((lane >> 4) & 3) ^ ((lane >> 1) & 3)) << 3);

  bf16x8 af[4], bf[4];
  auto rdA = [&](int d, int ks, int mq) {
    const u16* blk = smem + ((d * 2 + ks) << 13);
    #pragma unroll
    for (int m = 0; m < 4; ++m)
      af[m] = *(const bf16x8*)(blk + (wm * 128 + mq * 64 + m * 16 + lr) * 32 + lc);
  };
  auto rdB = [&](int d, int ks) {
    const u16* blk = smem + 32768 + ((d * 2 + ks) << 13);
    #pragma unroll
    for (int n = 0; n < 4; ++n)
      bf[n] = *(const bf16x8*)(blk + (wn * 64 + n * 16 + lr) * 32 + lc);
  };
  auto MF = [&](int mq) {
    __builtin_amdgcn_s_setprio(1);
    #pragma unroll
    for (int m = 0; m < 4; ++m)
      #pragma unroll
      for (int n = 0; n < 4; ++n)
        acc[mq * 4 + m][n] = __builtin_amdgcn_mfma_f32_16x16x32_bf16(
            af[m], bf[n], acc[mq * 4 + m][n], 0, 0, 0);
    __builtin_amdgcn_s_setprio(0);
  };

  stageA(0, 0, 0); stageA(0, 1, 0);
  stageB(0, 0, 0); stageB(0, 1, 0);
  vmwait(0);
  __builtin_amdgcn_s_barrier();
  CFENCE;

  for (int t = 0; t < NTK; ++t) {
    const int d = t & 1, dn = d ^ 1;
    const bool hasN = (t + 1 < NTK);
    rdB(d, 0); rdA(d, 0, 0);
    if (hasN) {
      stageA(dn, 0, t + 1); stageA(dn, 1, t + 1);
      stageB(dn, 0, t + 1); stageB(dn, 1, t + 1);
    }
    __builtin_amdgcn_sched_barrier(0);
    MF(0);
    rdA(d, 0, 1);
    MF(1);
    rdB(d, 1); rdA(d, 1, 0);
    MF(0);
    rdA(d, 1, 1);
    MF(1);
    vmwait(0);
    __builtin_amdgcn_s_barrier();
    CFENCE;
  }

  u16* D = dcomp + (size_t)e * TT * HH;
  const int rb = mt * 256 + wm * 128 + ((lane >> 4) << 2);
  const int cb = ntl * 256 + wn * 64 + lr;
  #pragma unroll
  for (int m = 0; m < 8; ++m)
    #pragma unroll
    for (int n = 0; n < 4; ++n)
      #pragma unroll
      for (int j = 0; j < 4; ++j)
        D[(size_t)(rb + m*16 + j) * HH + cb + n*16] = f2u(acc[m][n][j]);
}

// unified chain kernel: [down | GLU | tcast] by bid range (all ranges %8==0)
__global__ __launch_bounds__(512)
void k_chain(int nDown, int downE0, int nGlu, int gluE0, int tcastE0,
             const u16* __restrict__ xb, const int* __restrict__ cnt,
             const int* __restrict__ tok, const u16* __restrict__ Zp,
             u16* __restrict__ hc, const float* __restrict__ W1,
             const float* __restrict__ V1, const u16* __restrict__ w2t_c,
             u16* __restrict__ w2t, u16* __restrict__ dcomp,
             const float* __restrict__ W2) {
  __shared__ __align__(16) u16 smem[65536];
  const int bid = blockIdx.x;
  if (bid < nDown) {
    down_block(bid, downE0, smem, hc, w2t_c, cnt, dcomp);
  } else if (bid < nDown + nGlu) {
    glu_block(bid - nDown, gluE0, smem, xb, cnt, tok, Zp, hc, W1, V1);
  } else {
    tcast_block(bid - nDown - nGlu, tcastE0, smem, W2, w2t);
  }
}

__global__ void k_combine(const float* __restrict__ tw, const int* __restrict__ te,
                          const int* __restrict__ posmap, const u16* __restrict__ dcomp,
                          float* __restrict__ out) {
  const int t = blockIdx.x;
  const int c0 = threadIdx.x * 8;
  float a[8] = {0.f, 0.f, 0.f, 0.f, 0.f, 0.f, 0.f, 0.f};
  #pragma unroll
  for (int k = 0; k < KTOP; ++k) {
    const int e = te[t * KTOP + k];
    const float w = tw[t * KTOP + k];
    const int r = posmap[t * NE + e];
    const u16* row = dcomp + ((size_t)e * TT + r) * HH + c0;
    union { bf16x8 v; ushort u[8]; } x;
    x.v = *(const bf16x8*)row;
    #pragma unroll
    for (int j = 0; j < 8; ++j) a[j] += w * u2f(x.u[j]);
  }
  float* o = out + (size_t)t * HH + c0;
  ((float4*)o)[0] = (float4){a[0], a[1], a[2], a[3]};
  ((float4*)o)[1] = (float4){a[4], a[5], a[6], a[7]};
}

extern "C" void kernel_launch(void* const* d_in, const int* in_sizes, int n_in,
                              void* d_out, int out_size, void* d_ws, size_t ws_size,
                              hipStream_t stream) {
  const float* x  = (const float*)d_in[0];
  const float* tw = (const float*)d_in[2];
  const int*   te = (const int*)d_in[3];
  const float* w1 = (const float*)d_in[4];
  const float* v1 = (const float*)d_in[5];
  const float* w2 = (const float*)d_in[6];
  float* out = (float*)d_out;

  char* p = (char*)d_ws;
  int*   cnt    = (int*)p;   p += 256;
  int*   tok    = (int*)p;   p += (size_t)NE * TT * 4;
  int*   posmap = (int*)p;   p += (size_t)TT * NE * 4;
  u16*   zp     = (u16*)p;   p += (size_t)HH * 2;                 // 4 KB zeros
  u16*   xb     = (u16*)p;   p += (size_t)TT * HH * 2;            // 8 MB
  u16*   w2tb   = (u16*)p;   p += (size_t)NE * HH * FF * 2;       // 134 MB
  u16*   hc     = (u16*)p;   p += (size_t)NE * TT * FF * 2;       // 134 MB
  u16*   dcomp  = (u16*)p;   p += (size_t)NE * TT * HH * 2;       // 67 MB

  hipMemsetAsync(zp, 0, (size_t)HH * 2, stream);
  k_build<<<NE, 256, 0, stream>>>(te, cnt, tok, posmap);
  k_cast4<<<1024, 256, 0, stream>>>((const float4*)x, (ushort4*)xb, TT * HH / 4);

  // L1: GLU(e0,e1) + tcast(e0..e3)
  k_chain<<<512 + 1024, 512, 0, stream>>>(0, 0, 512, 0, 0,
      xb, cnt, tok, zp, hc, w1, v1, w2tb, w2tb, dcomp, w2);
  // L2: down(e0,e1) + GLU(e2,e3) + tcast(e4,e5)
  k_chain<<<128 + 512 + 512, 512, 0, stream>>>(128, 0, 512, 2, 4,
      xb, cnt, tok, zp, hc, w1, v1, w2tb, w2tb, dcomp, w2);
  // L3: down(e2,e3) + GLU(e4,e5) + tcast(e6,e7)
  k_chain<<<128 + 512 + 512, 512, 0, stream>>>(128, 2, 512, 4, 6,
      xb, cnt, tok, zp, hc, w1, v1, w2tb, w2tb, dcomp, w2);
  // L4: down(e4,e5) + GLU(e6,e7)
  k_chain<<<128 + 512, 512, 0, stream>>>(128, 4, 512, 6, 0,
      xb, cnt, tok, zp, hc, w1, v1, w2tb, w2tb, dcomp, w2);
  // L5: down(e6,e7)
  k_chain<<<128, 512, 0, stream>>>(128, 6, 0, 0, 0,
      xb, cnt, tok, zp, hc, w1, v1, w2tb, w2tb, dcomp, w2);

  k_combine<<<TT, 256, 0, stream>>>(tw, te, posmap, dcomp, out);
}

// Round 13
// 501.836 us; speedup vs baseline: 1.5133x; 1.5133x over previous
//
#include <hip/hip_runtime.h>
#include <hip/hip_bf16.h>

#define NE 8
#define FF 4096
#define HH 2048
#define TT 2048
#define KTOP 4

typedef unsigned short u16;
typedef unsigned int u32;
typedef __attribute__((ext_vector_type(8))) short bf16x8;
typedef __attribute__((ext_vector_type(4))) float f32x4;

#define CFENCE asm volatile("" ::: "memory")

__device__ __forceinline__ u16 f2u(float f) {
  __hip_bfloat16 b = __float2bfloat16(f);
  return *reinterpret_cast<u16*>(&b);
}
__device__ __forceinline__ float u2f(u16 u) {
  union { u32 i; float f; } c; c.i = ((u32)u) << 16; return c.f;
}

__device__ __forceinline__ void gld16(void* lds, const void* g) {
  __builtin_amdgcn_global_load_lds(
      (const __attribute__((address_space(1))) void*)g,
      (__attribute__((address_space(3))) void*)lds, 16, 0, 0);
}

// Per-expert token lists, deterministic (token ascending).
__global__ void k_build(const int* __restrict__ te, int* __restrict__ cnt,
                        int* __restrict__ tok, int* __restrict__ posmap) {
  const int e = blockIdx.x;
  const int tl = threadIdx.x;          // 256 threads, 8 tokens each
  const int base = tl * 8;
  int mem[8];
  int my = 0;
  #pragma unroll
  for (int i = 0; i < 8; ++i) {
    const int t = base + i;
    bool m = false;
    #pragma unroll
    for (int k = 0; k < KTOP; ++k) m |= (te[t * KTOP + k] == e);
    mem[i] = m ? 1 : 0;
    my += mem[i];
  }
  __shared__ int s[256];
  s[tl] = my;
  __syncthreads();
  for (int off = 1; off < 256; off <<= 1) {
    int v = (tl >= off) ? s[tl - off] : 0;
    __syncthreads();
    s[tl] += v;
    __syncthreads();
  }
  int r = s[tl] - my;
  if (tl == 255) cnt[e] = s[255];
  #pragma unroll
  for (int i = 0; i < 8; ++i) {
    if (mem[i]) {
      const int t = base + i;
      tok[e * TT + r] = t;
      posmap[t * NE + e] = r;
      ++r;
    }
  }
}

__global__ void k_cast4(const float4* __restrict__ src, ushort4* __restrict__ dst, int n4) {
  int stride = gridDim.x * blockDim.x;
  for (int i = blockIdx.x * blockDim.x + threadIdx.x; i < n4; i += stride) {
    float4 f = src[i];
    ushort4 o;
    o.x = f2u(f.x); o.y = f2u(f.y); o.z = f2u(f.z); o.w = f2u(f.w);
    dst[i] = o;
  }
}

// 256x256 bf16 GEMM, BK=64, 8 waves (2Mx4N). 2-barrier K-tile: all frag reads
// hit buffer d (stable across the tile), all staging writes go to dn; the
// interior {reads, MFMA, stage, cvt} is compiler-scheduled (hipcc emits counted
// lgkmcnt for ds_read->MFMA deps). sched_barrier(0) pins VMEM issue order so
// the exit vmcnt stays exact.
// LDS = [A|B][dbuf][ks][256 rows][32 cols] bf16, granule swz g^((r>>1)&3).
// MODE 0 (GLU): A gathered from xb via tok[]; B reg-staged from W1/V1 fp32
//   (1.5-tile lookahead: issueB(t+2) right after cvtB(t+1) frees regs).
//   Blocks with bid>=2048 instead transpose-cast w2 -> w2t (fused tcast).
// MODE 1 (down): A=hc, B=w2t, both via gld_lds, full t+1 stage per tile.
//   Output dcomp in BF16 (halves write + combine-read traffic).
// Block order: swz stride-8 (each XCD ~ one expert), mt inner (B L2 reuse).
template<int MODE>
__global__ __launch_bounds__(512)
void gemm256(const u16* __restrict__ Aall, const u16* __restrict__ Ball,
             const int* __restrict__ cnt, void* __restrict__ Oall,
             const float* __restrict__ W1, const float* __restrict__ V1,
             const int* __restrict__ tok, const u16* __restrict__ Zp,
             const float* __restrict__ W2, u16* __restrict__ W2t) {
  constexpr int KD  = (MODE == 0) ? HH : FF;   // 2048 / 4096
  constexpr int NTK = KD / 64;                 // 32 / 64 K-tiles
  constexpr int NT  = (MODE == 0) ? 32 : 8;    // N tiles
  constexpr int NB  = (MODE == 0) ? 2 * FF : HH;
  constexpr int NWG = (MODE == 0) ? 2048 : 512;  // GEMM blocks (excl. tcast)

  __shared__ __align__(16) u16 smem[65536];    // 128 KB
  const int bid = blockIdx.x;
  const int tid = threadIdx.x;

  if (MODE == 0 && bid >= NWG) {
    // ---- fused transpose-cast: w2[e][FF][HH] fp32 -> w2t[e][HH][FF] bf16 ----
    float (*tile)[65] = reinterpret_cast<float(*)[65]>(smem);  // 64x65 f32
    const int r = tid >> 3;
    const int c0 = (tid & 7) * 8;
    for (int i = 0; i < 8; ++i) {
      const int g = (bid - NWG) * 8 + i;       // 16384 tiles total
      const int e = g >> 11;
      const int rem = g & 2047;
      const int f0 = (rem >> 5) << 6;
      const int h0 = (rem & 31) << 6;
      const float* src = W2 + (size_t)e * FF * HH + (size_t)(f0 + r) * HH + h0 + c0;
      float4 a = ((const float4*)src)[0];
      float4 b = ((const float4*)src)[1];
      tile[r][c0 + 0] = a.x; tile[r][c0 + 1] = a.y;
      tile[r][c0 + 2] = a.z; tile[r][c0 + 3] = a.w;
      tile[r][c0 + 4] = b.x; tile[r][c0 + 5] = b.y;
      tile[r][c0 + 6] = b.z; tile[r][c0 + 7] = b.w;
      __syncthreads();
      union { ushort u[8]; bf16x8 v; } o;
      #pragma unroll
      for (int j = 0; j < 8; ++j) o.u[j] = f2u(tile[c0 + j][r]);
      *(bf16x8*)(W2t + (size_t)e * HH * FF + (size_t)(h0 + r) * FF + f0 + c0) = o.v;
      __syncthreads();
    }
    return;
  }

  const int swz = (bid & 7) * (NWG >> 3) + (bid >> 3);
  const int e   = swz / (8 * NT);
  const int rem = swz % (8 * NT);
  const int ntl = rem / 8;        // B tile (outer)
  const int mt  = rem % 8;        // A tile (inner)
  const int c = cnt[e];
  const int mcap = (c + 255) & ~255;
  if (mt * 256 >= mcap) return;

  const int lane = tid & 63;
  const int wave = tid >> 6;
  const int wm = wave >> 2;
  const int wn = wave & 3;

  const int tq = tid >> 2;                                 // row 0..127 (+128)
  const int tc = (((tid & 3) ^ ((tid >> 3) & 3)) << 3);    // swizzled granule, u16

  // A sources
  const u16* pA0;
  const u16* pA1;
  if constexpr (MODE == 0) {
    const int r0 = mt * 256 + tq;
    const int r1 = r0 + 128;
    pA0 = ((r0 < c) ? Aall + (size_t)tok[e * TT + r0] * HH : Zp) + tc;
    pA1 = ((r1 < c) ? Aall + (size_t)tok[e * TT + r1] * HH : Zp) + tc;
  } else {
    const u16* A = Aall + (size_t)e * TT * KD + (size_t)(mt * 256) * KD;
    pA0 = A + (size_t)tq * KD + tc;
    pA1 = pA0 + (size_t)128 * KD;
  }

  auto stageA = [&](int d, int ks, int kt) {
    u16* dst = smem + ((d * 2 + ks) << 13) + tid * 8;
    const int off = kt * 64 + ks * 32;
    gld16(dst,        pA0 + off);
    gld16(dst + 4096, pA1 + off);
  };

  const u16* pB = Ball + (size_t)e * NB * KD + (size_t)(ntl * 256) * KD
                       + (size_t)tq * KD + tc;
  auto stageB = [&](int d, int ks, int kt) {
    u16* dst = smem + 32768 + ((d * 2 + ks) << 13) + tid * 8;
    const u16* src = pB + kt * 64 + ks * 32;
    gld16(dst,        src);
    gld16(dst + 4096, src + (size_t)128 * KD);
  };

  // MODE 0: B reg-staged from W1/V1 fp32 (linear source, swizzle on ds_write)
  const float* pW = nullptr;
  if constexpr (MODE == 0) {
    const int sel = (tq >> 4) & 1;
    const int fr  = ntl * 128 + (tq >> 5) * 16 + (tq & 15);
    pW = (sel ? V1 : W1) + ((size_t)(e * FF + fr)) * HH + (tid & 3) * 8;
  }
  float4 br0[4], br1[4];
  auto issueB = [&](float4* br, int ks, int kt) {
    const float* s = pW + kt * 64 + ks * 32;
    br[0] = ((const float4*)s)[0];
    br[1] = ((const float4*)s)[1];
    const float* s2 = s + (size_t)64 * HH;    // row +128 => f+64, same matrix
    br[2] = ((const float4*)s2)[0];
    br[3] = ((const float4*)s2)[1];
  };
  auto cvtB = [&](float4* br, int d, int ks) {
    u16* dst = smem + 32768 + ((d * 2 + ks) << 13) + tq * 32 + tc;
    union { ushort u[8]; bf16x8 v; } lo, hi;
    lo.u[0]=f2u(br[0].x); lo.u[1]=f2u(br[0].y); lo.u[2]=f2u(br[0].z); lo.u[3]=f2u(br[0].w);
    lo.u[4]=f2u(br[1].x); lo.u[5]=f2u(br[1].y); lo.u[6]=f2u(br[1].z); lo.u[7]=f2u(br[1].w);
    hi.u[0]=f2u(br[2].x); hi.u[1]=f2u(br[2].y); hi.u[2]=f2u(br[2].z); hi.u[3]=f2u(br[2].w);
    hi.u[4]=f2u(br[3].x); hi.u[5]=f2u(br[3].y); hi.u[6]=f2u(br[3].z); hi.u[7]=f2u(br[3].w);
    *(bf16x8*)(dst)        = lo.v;
    *(bf16x8*)(dst + 4096) = hi.v;
  };

  f32x4 acc[8][4];
  #pragma unroll
  for (int m = 0; m < 8; ++m)
    #pragma unroll
    for (int n = 0; n < 4; ++n)
      acc[m][n] = (f32x4){0.f, 0.f, 0.f, 0.f};

  const int lr = lane & 15;
  const int lc = ((((lane >> 4) & 3) ^ ((lane >> 1) & 3)) << 3);

  bf16x8 af[4], bf[4];
  auto rdA = [&](int d, int ks, int mq) {
    const u16* blk = smem + ((d * 2 + ks) << 13);
    #pragma unroll
    for (int m = 0; m < 4; ++m)
      af[m] = *(const bf16x8*)(blk + (wm * 128 + mq * 64 + m * 16 + lr) * 32 + lc);
  };
  auto rdB = [&](int d, int ks) {
    const u16* blk = smem + 32768 + ((d * 2 + ks) << 13);
    #pragma unroll
    for (int n = 0; n < 4; ++n)
      bf[n] = *(const bf16x8*)(blk + (wn * 64 + n * 16 + lr) * 32 + lc);
  };
  auto vmwait = [&](int n) {
    switch (n) {
      case 0:  asm volatile("s_waitcnt vmcnt(0)"  ::: "memory"); break;
      case 6:  asm volatile("s_waitcnt vmcnt(6)"  ::: "memory"); break;
      default: asm volatile("s_waitcnt vmcnt(8)"  ::: "memory"); break;
    }
  };
  auto MF = [&](int mq) {
    __builtin_amdgcn_s_setprio(1);
    #pragma unroll
    for (int m = 0; m < 4; ++m)
      #pragma unroll
      for (int n = 0; n < 4; ++n)
        acc[mq * 4 + m][n] = __builtin_amdgcn_mfma_f32_16x16x32_bf16(
            af[m], bf[n], acc[mq * 4 + m][n], 0, 0, 0);
    __builtin_amdgcn_s_setprio(0);
  };

  // ---- prologue: tile 0 into dbuf 0; B(t1) issued, cvt'd during t0 ----
  if constexpr (MODE == 0) {
    issueB(br0, 0, 0);
    issueB(br1, 1, 0);
    stageA(0, 0, 0);
    stageA(0, 1, 0);
    cvtB(br0, 0, 0);          // auto-wait drains br0
    cvtB(br1, 0, 1);          // auto-wait drains br1
    issueB(br0, 0, 1);        // B(t1), cvt'd during t0 into dbuf 1
    issueB(br1, 1, 1);
    vmwait(8);                // drain A(t0); B(t1) 8 stay in flight
    asm volatile("s_waitcnt lgkmcnt(0)" ::: "memory");
  } else {
    stageA(0, 0, 0); stageA(0, 1, 0);
    stageB(0, 0, 0); stageB(0, 1, 0);
    vmwait(0);
  }
  __builtin_amdgcn_s_barrier();
  CFENCE;

  // ---- main loop: one barrier pair per K-tile, compiler-scheduled interior --
  for (int t = 0; t < NTK; ++t) {
    const int d = t & 1, dn = d ^ 1;
    const bool hasN  = (t + 1 < NTK);
    const bool hasN2 = (t + 2 < NTK);

    // phase 0 reads + all gld_lds staging for t+1 (issue order pinned below)
    rdB(d, 0); rdA(d, 0, 0);
    if (hasN) {
      stageA(dn, 0, t + 1);
      stageA(dn, 1, t + 1);
      if constexpr (MODE == 1) { stageB(dn, 0, t + 1); stageB(dn, 1, t + 1); }
    }
    __builtin_amdgcn_sched_barrier(0);
    MF(0);
    rdA(d, 0, 1);
    MF(1);
    if constexpr (MODE == 0) {
      if (hasN)  cvtB(br0, dn, 0);        // ds_writes for t+1 ks0
      if (hasN2) issueB(br0, 0, t + 2);   // refill (4-phase latency cover)
    }
    rdB(d, 1); rdA(d, 1, 0);
    MF(0);
    if constexpr (MODE == 0) {
      if (hasN)  cvtB(br1, dn, 1);
      if (hasN2) issueB(br1, 1, t + 2);
    }
    rdA(d, 1, 1);
    MF(1);
    if constexpr (MODE == 0) {
      asm volatile("s_waitcnt lgkmcnt(0)" ::: "memory");  // cvt writes drained
      vmwait(hasN2 ? 8 : 0);    // drain A(t+1) gld_lds; keep B(t+2) in flight
    } else {
      vmwait(0);                // drain the 8 gld_lds for t+1
    }
    __builtin_amdgcn_s_barrier();
    CFENCE;
  }

  // C/D: col = lane&15, row = (lane>>4)*4 + j  (verified)
  const int rb = mt * 256 + wm * 128 + ((lane >> 4) << 2);
  if (MODE == 0) {
    u16* H = (u16*)Oall + (size_t)e * TT * FF;
    const int fb = ntl * 128 + wn * 32 + lr;
    #pragma unroll
    for (int m = 0; m < 8; ++m)
      #pragma unroll
      for (int np = 0; np < 2; ++np)
        #pragma unroll
        for (int j = 0; j < 4; ++j) {
          float g = acc[m][2*np][j];
          float u = acc[m][2*np + 1][j];
          float hh = (g / (1.f + __expf(-g))) * u;
          H[(size_t)(rb + m*16 + j) * FF + fb + np*16] = f2u(hh);
        }
  } else {
    u16* D = (u16*)Oall + (size_t)e * TT * HH;
    const int cb = ntl * 256 + wn * 64 + lr;
    #pragma unroll
    for (int m = 0; m < 8; ++m)
      #pragma unroll
      for (int n = 0; n < 4; ++n)
        #pragma unroll
        for (int j = 0; j < 4; ++j)
          D[(size_t)(rb + m*16 + j) * HH + cb + n*16] = f2u(acc[m][n][j]);
  }
}

__global__ void k_combine(const float* __restrict__ tw, const int* __restrict__ te,
                          const int* __restrict__ posmap, const u16* __restrict__ dcomp,
                          float* __restrict__ out) {
  const int t = blockIdx.x;
  const int c0 = threadIdx.x * 8;
  float a[8] = {0.f, 0.f, 0.f, 0.f, 0.f, 0.f, 0.f, 0.f};
  #pragma unroll
  for (int k = 0; k < KTOP; ++k) {
    const int e = te[t * KTOP + k];
    const float w = tw[t * KTOP + k];
    const int r = posmap[t * NE + e];
    const u16* row = dcomp + ((size_t)e * TT + r) * HH + c0;
    union { bf16x8 v; ushort u[8]; } x;
    x.v = *(const bf16x8*)row;
    #pragma unroll
    for (int j = 0; j < 8; ++j) a[j] += w * u2f(x.u[j]);
  }
  float* o = out + (size_t)t * HH + c0;
  ((float4*)o)[0] = (float4){a[0], a[1], a[2], a[3]};
  ((float4*)o)[1] = (float4){a[4], a[5], a[6], a[7]};
}

extern "C" void kernel_launch(void* const* d_in, const int* in_sizes, int n_in,
                              void* d_out, int out_size, void* d_ws, size_t ws_size,
                              hipStream_t stream) {
  const float* x  = (const float*)d_in[0];
  const float* tw = (const float*)d_in[2];
  const int*   te = (const int*)d_in[3];
  const float* w1 = (const float*)d_in[4];
  const float* v1 = (const float*)d_in[5];
  const float* w2 = (const float*)d_in[6];
  float* out = (float*)d_out;

  char* p = (char*)d_ws;
  int*   cnt    = (int*)p;   p += 256;
  int*   tok    = (int*)p;   p += (size_t)NE * TT * 4;
  int*   posmap = (int*)p;   p += (size_t)TT * NE * 4;
  u16*   zp     = (u16*)p;   p += (size_t)HH * 2;                 // 4 KB zeros
  u16*   xb     = (u16*)p;   p += (size_t)TT * HH * 2;            // 8 MB
  u16*   w2tb   = (u16*)p;   p += (size_t)NE * HH * FF * 2;       // 134 MB
  u16*   hc     = (u16*)p;   p += (size_t)NE * TT * FF * 2;       // 134 MB
  u16*   dcomp  = (u16*)p;   p += (size_t)NE * TT * HH * 2;       // 67 MB

  hipMemsetAsync(zp, 0, (size_t)HH * 2, stream);   // zero page for pad rows
  k_build<<<NE, 256, 0, stream>>>(te, cnt, tok, posmap);
  k_cast4<<<1024, 256, 0, stream>>>((const float4*)x, (ushort4*)xb, TT * HH / 4);

  // GLU (2048 blocks) + fused w2 transpose-cast (2048 blocks)
  gemm256<0><<<4096, 512, 0, stream>>>(xb, nullptr, cnt, hc, w1, v1, tok, zp,
                                       w2, w2tb);
  // down: 8 e x 8 ntl x 8 mt = 512 blocks
  gemm256<1><<<512, 512, 0, stream>>>(hc, w2tb, cnt, dcomp, nullptr, nullptr,
                                      nullptr, nullptr, nullptr, nullptr);
  k_combine<<<TT, 256, 0, stream>>>(tw, te, posmap, dcomp, out);
}

// Round 14
// 487.291 us; speedup vs baseline: 1.5584x; 1.0298x over previous
//
#include <hip/hip_runtime.h>
#include <hip/hip_bf16.h>

#define NE 8
#define FF 4096
#define HH 2048
#define TT 2048
#define KTOP 4

typedef unsigned short u16;
typedef unsigned int u32;
typedef __attribute__((ext_vector_type(8))) short bf16x8;
typedef __attribute__((ext_vector_type(4))) float f32x4;

#define CFENCE asm volatile("" ::: "memory")

__device__ __forceinline__ u16 f2u(float f) {
  __hip_bfloat16 b = __float2bfloat16(f);
  return *reinterpret_cast<u16*>(&b);
}
__device__ __forceinline__ float u2f(u16 u) {
  union { u32 i; float f; } c; c.i = ((u32)u) << 16; return c.f;
}

__device__ __forceinline__ void gld16(void* lds, const void* g) {
  __builtin_amdgcn_global_load_lds(
      (const __attribute__((address_space(1))) void*)g,
      (__attribute__((address_space(3))) void*)lds, 16, 0, 0);
}

// Per-expert token lists, deterministic (token ascending).
__global__ void k_build(const int* __restrict__ te, int* __restrict__ cnt,
                        int* __restrict__ tok, int* __restrict__ posmap) {
  const int e = blockIdx.x;
  const int tl = threadIdx.x;          // 256 threads, 8 tokens each
  const int base = tl * 8;
  int mem[8];
  int my = 0;
  #pragma unroll
  for (int i = 0; i < 8; ++i) {
    const int t = base + i;
    bool m = false;
    #pragma unroll
    for (int k = 0; k < KTOP; ++k) m |= (te[t * KTOP + k] == e);
    mem[i] = m ? 1 : 0;
    my += mem[i];
  }
  __shared__ int s[256];
  s[tl] = my;
  __syncthreads();
  for (int off = 1; off < 256; off <<= 1) {
    int v = (tl >= off) ? s[tl - off] : 0;
    __syncthreads();
    s[tl] += v;
    __syncthreads();
  }
  int r = s[tl] - my;
  if (tl == 255) cnt[e] = s[255];
  #pragma unroll
  for (int i = 0; i < 8; ++i) {
    if (mem[i]) {
      const int t = base + i;
      tok[e * TT + r] = t;
      posmap[t * NE + e] = r;
      ++r;
    }
  }
}

__global__ void k_cast4(const float4* __restrict__ src, ushort4* __restrict__ dst, int n4) {
  int stride = gridDim.x * blockDim.x;
  for (int i = blockIdx.x * blockDim.x + threadIdx.x; i < n4; i += stride) {
    float4 f = src[i];
    ushort4 o;
    o.x = f2u(f.x); o.y = f2u(f.y); o.z = f2u(f.z); o.w = f2u(f.w);
    dst[i] = o;
  }
}

// 256x256 bf16 GEMM, BK=64, 8 waves (2Mx4N). 2-barrier K-tile (R13-proven).
// NEW (R14): pad-skip — waves whose 128-row span is entirely >= cnt skip all
// frag reads + MFMA + epilogue (wave-uniform branch; staging/barriers/vmcnt
// identical, so the counted-vmcnt accounting is unchanged). Skipped hc/dcomp
// rows stay uninitialized; they are only consumed as pad (never read by
// k_combine, garbage-in-garbage-out through the down GEMM).
// LDS = [A|B][dbuf][ks][256 rows][32 cols] bf16, granule swz g^((r>>1)&3).
// MODE 0 (GLU): A gathered from xb via tok[]; B reg-staged from W1/V1 fp32;
//   bid>=2048 blocks do the fused w2 transpose-cast instead.
// MODE 1 (down): A=hc, B=w2t via gld_lds; dcomp bf16 out.
// Block order: swz stride-8 (each XCD ~ one expert), mt inner (B L2 reuse).
template<int MODE>
__global__ __launch_bounds__(512)
void gemm256(const u16* __restrict__ Aall, const u16* __restrict__ Ball,
             const int* __restrict__ cnt, void* __restrict__ Oall,
             const float* __restrict__ W1, const float* __restrict__ V1,
             const int* __restrict__ tok, const u16* __restrict__ Zp,
             const float* __restrict__ W2, u16* __restrict__ W2t) {
  constexpr int KD  = (MODE == 0) ? HH : FF;   // 2048 / 4096
  constexpr int NTK = KD / 64;                 // 32 / 64 K-tiles
  constexpr int NT  = (MODE == 0) ? 32 : 8;    // N tiles
  constexpr int NB  = (MODE == 0) ? 2 * FF : HH;
  constexpr int NWG = (MODE == 0) ? 2048 : 512;  // GEMM blocks (excl. tcast)

  __shared__ __align__(16) u16 smem[65536];    // 128 KB
  const int bid = blockIdx.x;
  const int tid = threadIdx.x;

  if (MODE == 0 && bid >= NWG) {
    // ---- fused transpose-cast: w2[e][FF][HH] fp32 -> w2t[e][HH][FF] bf16 ----
    float (*tile)[65] = reinterpret_cast<float(*)[65]>(smem);  // 64x65 f32
    const int r = tid >> 3;
    const int c0 = (tid & 7) * 8;
    for (int i = 0; i < 8; ++i) {
      const int g = (bid - NWG) * 8 + i;       // 16384 tiles total
      const int e = g >> 11;
      const int rem = g & 2047;
      const int f0 = (rem >> 5) << 6;
      const int h0 = (rem & 31) << 6;
      const float* src = W2 + (size_t)e * FF * HH + (size_t)(f0 + r) * HH + h0 + c0;
      float4 a = ((const float4*)src)[0];
      float4 b = ((const float4*)src)[1];
      tile[r][c0 + 0] = a.x; tile[r][c0 + 1] = a.y;
      tile[r][c0 + 2] = a.z; tile[r][c0 + 3] = a.w;
      tile[r][c0 + 4] = b.x; tile[r][c0 + 5] = b.y;
      tile[r][c0 + 6] = b.z; tile[r][c0 + 7] = b.w;
      __syncthreads();
      union { ushort u[8]; bf16x8 v; } o;
      #pragma unroll
      for (int j = 0; j < 8; ++j) o.u[j] = f2u(tile[c0 + j][r]);
      *(bf16x8*)(W2t + (size_t)e * HH * FF + (size_t)(h0 + r) * FF + f0 + c0) = o.v;
      __syncthreads();
    }
    return;
  }

  const int swz = (bid & 7) * (NWG >> 3) + (bid >> 3);
  const int e   = swz / (8 * NT);
  const int rem = swz % (8 * NT);
  const int ntl = rem / 8;        // B tile (outer)
  const int mt  = rem % 8;        // A tile (inner)
  const int c = cnt[e];
  const int mcap = (c + 255) & ~255;
  if (mt * 256 >= mcap) return;

  const int lane = tid & 63;
  const int wave = tid >> 6;
  const int wm = wave >> 2;
  const int wn = wave & 3;

  // pad-skip: this wave's 128-row span [mt*256 + wm*128, +128) entirely pad?
  const bool skipW = (wm == 1) && (mt * 256 + 128 >= c);

  const int tq = tid >> 2;                                 // row 0..127 (+128)
  const int tc = (((tid & 3) ^ ((tid >> 3) & 3)) << 3);    // swizzled granule, u16

  // A sources
  const u16* pA0;
  const u16* pA1;
  if constexpr (MODE == 0) {
    const int r0 = mt * 256 + tq;
    const int r1 = r0 + 128;
    pA0 = ((r0 < c) ? Aall + (size_t)tok[e * TT + r0] * HH : Zp) + tc;
    pA1 = ((r1 < c) ? Aall + (size_t)tok[e * TT + r1] * HH : Zp) + tc;
  } else {
    const u16* A = Aall + (size_t)e * TT * KD + (size_t)(mt * 256) * KD;
    pA0 = A + (size_t)tq * KD + tc;
    pA1 = pA0 + (size_t)128 * KD;
  }

  auto stageA = [&](int d, int ks, int kt) {
    u16* dst = smem + ((d * 2 + ks) << 13) + tid * 8;
    const int off = kt * 64 + ks * 32;
    gld16(dst,        pA0 + off);
    gld16(dst + 4096, pA1 + off);
  };

  const u16* pB = Ball + (size_t)e * NB * KD + (size_t)(ntl * 256) * KD
                       + (size_t)tq * KD + tc;
  auto stageB = [&](int d, int ks, int kt) {
    u16* dst = smem + 32768 + ((d * 2 + ks) << 13) + tid * 8;
    const u16* src = pB + kt * 64 + ks * 32;
    gld16(dst,        src);
    gld16(dst + 4096, src + (size_t)128 * KD);
  };

  // MODE 0: B reg-staged from W1/V1 fp32 (linear source, swizzle on ds_write)
  const float* pW = nullptr;
  if constexpr (MODE == 0) {
    const int sel = (tq >> 4) & 1;
    const int fr  = ntl * 128 + (tq >> 5) * 16 + (tq & 15);
    pW = (sel ? V1 : W1) + ((size_t)(e * FF + fr)) * HH + (tid & 3) * 8;
  }
  float4 br0[4], br1[4];
  auto issueB = [&](float4* br, int ks, int kt) {
    const float* s = pW + kt * 64 + ks * 32;
    br[0] = ((const float4*)s)[0];
    br[1] = ((const float4*)s)[1];
    const float* s2 = s + (size_t)64 * HH;    // row +128 => f+64, same matrix
    br[2] = ((const float4*)s2)[0];
    br[3] = ((const float4*)s2)[1];
  };
  auto cvtB = [&](float4* br, int d, int ks) {
    u16* dst = smem + 32768 + ((d * 2 + ks) << 13) + tq * 32 + tc;
    union { ushort u[8]; bf16x8 v; } lo, hi;
    lo.u[0]=f2u(br[0].x); lo.u[1]=f2u(br[0].y); lo.u[2]=f2u(br[0].z); lo.u[3]=f2u(br[0].w);
    lo.u[4]=f2u(br[1].x); lo.u[5]=f2u(br[1].y); lo.u[6]=f2u(br[1].z); lo.u[7]=f2u(br[1].w);
    hi.u[0]=f2u(br[2].x); hi.u[1]=f2u(br[2].y); hi.u[2]=f2u(br[2].z); hi.u[3]=f2u(br[2].w);
    hi.u[4]=f2u(br[3].x); hi.u[5]=f2u(br[3].y); hi.u[6]=f2u(br[3].z); hi.u[7]=f2u(br[3].w);
    *(bf16x8*)(dst)        = lo.v;
    *(bf16x8*)(dst + 4096) = hi.v;
  };

  f32x4 acc[8][4];
  #pragma unroll
  for (int m = 0; m < 8; ++m)
    #pragma unroll
    for (int n = 0; n < 4; ++n)
      acc[m][n] = (f32x4){0.f, 0.f, 0.f, 0.f};

  const int lr = lane & 15;
  const int lc = ((((lane >> 4) & 3) ^ ((lane >> 1) & 3)) << 3);

  bf16x8 af[4], bf[4];
  auto rdA = [&](int d, int ks, int mq) {
    const u16* blk = smem + ((d * 2 + ks) << 13);
    #pragma unroll
    for (int m = 0; m < 4; ++m)
      af[m] = *(const bf16x8*)(blk + (wm * 128 + mq * 64 + m * 16 + lr) * 32 + lc);
  };
  auto rdB = [&](int d, int ks) {
    const u16* blk = smem + 32768 + ((d * 2 + ks) << 13);
    #pragma unroll
    for (int n = 0; n < 4; ++n)
      bf[n] = *(const bf16x8*)(blk + (wn * 64 + n * 16 + lr) * 32 + lc);
  };
  auto vmwait = [&](int n) {
    switch (n) {
      case 0:  asm volatile("s_waitcnt vmcnt(0)"  ::: "memory"); break;
      case 6:  asm volatile("s_waitcnt vmcnt(6)"  ::: "memory"); break;
      default: asm volatile("s_waitcnt vmcnt(8)"  ::: "memory"); break;
    }
  };
  auto MF = [&](int mq) {
    __builtin_amdgcn_s_setprio(1);
    #pragma unroll
    for (int m = 0; m < 4; ++m)
      #pragma unroll
      for (int n = 0; n < 4; ++n)
        acc[mq * 4 + m][n] = __builtin_amdgcn_mfma_f32_16x16x32_bf16(
            af[m], bf[n], acc[mq * 4 + m][n], 0, 0, 0);
    __builtin_amdgcn_s_setprio(0);
  };

  // ---- prologue: tile 0 into dbuf 0; B(t1) issued, cvt'd during t0 ----
  if constexpr (MODE == 0) {
    issueB(br0, 0, 0);
    issueB(br1, 1, 0);
    stageA(0, 0, 0);
    stageA(0, 1, 0);
    cvtB(br0, 0, 0);          // auto-wait drains br0
    cvtB(br1, 0, 1);          // auto-wait drains br1
    issueB(br0, 0, 1);        // B(t1), cvt'd during t0 into dbuf 1
    issueB(br1, 1, 1);
    vmwait(8);                // drain A(t0); B(t1) 8 stay in flight
    asm volatile("s_waitcnt lgkmcnt(0)" ::: "memory");
  } else {
    stageA(0, 0, 0); stageA(0, 1, 0);
    stageB(0, 0, 0); stageB(0, 1, 0);
    vmwait(0);
  }
  __builtin_amdgcn_s_barrier();
  CFENCE;

  // ---- main loop: one barrier pair per K-tile, compiler-scheduled interior --
  for (int t = 0; t < NTK; ++t) {
    const int d = t & 1, dn = d ^ 1;
    const bool hasN  = (t + 1 < NTK);
    const bool hasN2 = (t + 2 < NTK);

    // phase 0 reads + all gld_lds staging for t+1 (issue order pinned below)
    if (!skipW) { rdB(d, 0); rdA(d, 0, 0); }
    if (hasN) {
      stageA(dn, 0, t + 1);
      stageA(dn, 1, t + 1);
      if constexpr (MODE == 1) { stageB(dn, 0, t + 1); stageB(dn, 1, t + 1); }
    }
    __builtin_amdgcn_sched_barrier(0);
    if (!skipW) {
      MF(0);
      rdA(d, 0, 1);
      MF(1);
    }
    if constexpr (MODE == 0) {
      if (hasN)  cvtB(br0, dn, 0);        // ds_writes for t+1 ks0
      if (hasN2) issueB(br0, 0, t + 2);   // refill (4-phase latency cover)
    }
    if (!skipW) {
      rdB(d, 1); rdA(d, 1, 0);
      MF(0);
    }
    if constexpr (MODE == 0) {
      if (hasN)  cvtB(br1, dn, 1);
      if (hasN2) issueB(br1, 1, t + 2);
    }
    if (!skipW) {
      rdA(d, 1, 1);
      MF(1);
    }
    if constexpr (MODE == 0) {
      asm volatile("s_waitcnt lgkmcnt(0)" ::: "memory");  // cvt writes drained
      vmwait(hasN2 ? 8 : 0);    // drain A(t+1) gld_lds; keep B(t+2) in flight
    } else {
      vmwait(0);                // drain the 8 gld_lds for t+1
    }
    __builtin_amdgcn_s_barrier();
    CFENCE;
  }

  if (skipW) return;   // pad rows: no epilogue (rows never read downstream)

  // C/D: col = lane&15, row = (lane>>4)*4 + j  (verified)
  const int rb = mt * 256 + wm * 128 + ((lane >> 4) << 2);
  if (MODE == 0) {
    u16* H = (u16*)Oall + (size_t)e * TT * FF;
    const int fb = ntl * 128 + wn * 32 + lr;
    #pragma unroll
    for (int m = 0; m < 8; ++m)
      #pragma unroll
      for (int np = 0; np < 2; ++np)
        #pragma unroll
        for (int j = 0; j < 4; ++j) {
          float g = acc[m][2*np][j];
          float u = acc[m][2*np + 1][j];
          float hh = (g / (1.f + __expf(-g))) * u;
          H[(size_t)(rb + m*16 + j) * FF + fb + np*16] = f2u(hh);
        }
  } else {
    u16* D = (u16*)Oall + (size_t)e * TT * HH;
    const int cb = ntl * 256 + wn * 64 + lr;
    #pragma unroll
    for (int m = 0; m < 8; ++m)
      #pragma unroll
      for (int n = 0; n < 4; ++n)
        #pragma unroll
        for (int j = 0; j < 4; ++j)
          D[(size_t)(rb + m*16 + j) * HH + cb + n*16] = f2u(acc[m][n][j]);
  }
}

__global__ void k_combine(const float* __restrict__ tw, const int* __restrict__ te,
                          const int* __restrict__ posmap, const u16* __restrict__ dcomp,
                          float* __restrict__ out) {
  const int t = blockIdx.x;
  const int c0 = threadIdx.x * 8;
  float a[8] = {0.f, 0.f, 0.f, 0.f, 0.f, 0.f, 0.f, 0.f};
  #pragma unroll
  for (int k = 0; k < KTOP; ++k) {
    const int e = te[t * KTOP + k];
    const float w = tw[t * KTOP + k];
    const int r = posmap[t * NE + e];
    const u16* row = dcomp + ((size_t)e * TT + r) * HH + c0;
    union { bf16x8 v; ushort u[8]; } x;
    x.v = *(const bf16x8*)row;
    #pragma unroll
    for (int j = 0; j < 8; ++j) a[j] += w * u2f(x.u[j]);
  }
  float* o = out + (size_t)t * HH + c0;
  ((float4*)o)[0] = (float4){a[0], a[1], a[2], a[3]};
  ((float4*)o)[1] = (float4){a[4], a[5], a[6], a[7]};
}

extern "C" void kernel_launch(void* const* d_in, const int* in_sizes, int n_in,
                              void* d_out, int out_size, void* d_ws, size_t ws_size,
                              hipStream_t stream) {
  const float* x  = (const float*)d_in[0];
  const float* tw = (const float*)d_in[2];
  const int*   te = (const int*)d_in[3];
  const float* w1 = (const float*)d_in[4];
  const float* v1 = (const float*)d_in[5];
  const float* w2 = (const float*)d_in[6];
  float* out = (float*)d_out;

  char* p = (char*)d_ws;
  int*   cnt    = (int*)p;   p += 256;
  int*   tok    = (int*)p;   p += (size_t)NE * TT * 4;
  int*   posmap = (int*)p;   p += (size_t)TT * NE * 4;
  u16*   zp     = (u16*)p;   p += (size_t)HH * 2;                 // 4 KB zeros
  u16*   xb     = (u16*)p;   p += (size_t)TT * HH * 2;            // 8 MB
  u16*   w2tb   = (u16*)p;   p += (size_t)NE * HH * FF * 2;       // 134 MB
  u16*   hc     = (u16*)p;   p += (size_t)NE * TT * FF * 2;       // 134 MB
  u16*   dcomp  = (u16*)p;   p += (size_t)NE * TT * HH * 2;       // 67 MB

  hipMemsetAsync(zp, 0, (size_t)HH * 2, stream);   // zero page for pad rows
  k_build<<<NE, 256, 0, stream>>>(te, cnt, tok, posmap);
  k_cast4<<<1024, 256, 0, stream>>>((const float4*)x, (ushort4*)xb, TT * HH / 4);

  // GLU (2048 blocks) + fused w2 transpose-cast (2048 blocks)
  gemm256<0><<<4096, 512, 0, stream>>>(xb, nullptr, cnt, hc, w1, v1, tok, zp,
                                       w2, w2tb);
  // down: 8 e x 8 ntl x 8 mt = 512 blocks
  gemm256<1><<<512, 512, 0, stream>>>(hc, w2tb, cnt, dcomp, nullptr, nullptr,
                                      nullptr, nullptr, nullptr, nullptr);
  k_combine<<<TT, 256, 0, stream>>>(tw, te, posmap, dcomp, out);
}